// Round 4
// baseline (261.653 us; speedup 1.0000x reference)
//
#include <hip/hip_runtime.h>
#include <cstdint>
#include <cstddef>

// Problem constants (B=1, S=4096, H=1024, 16 heads x 64)
#define S_LEN 4096
#define NHEADS 16
#define HD 64
#define HDIM 1024

typedef _Float16 f16x8 __attribute__((ext_vector_type(8)));
typedef _Float16 f16x4 __attribute__((ext_vector_type(4)));
typedef __fp16 h16x2 __attribute__((ext_vector_type(2)));   // cvt_pkrtz native
typedef float f32x4 __attribute__((ext_vector_type(4)));
typedef unsigned char uchar;
typedef unsigned int u32;

__device__ __forceinline__ f32x4 mfma16h(f16x8 a, f16x8 b, f32x4 c) {
    return __builtin_amdgcn_mfma_f32_16x16x32_f16(a, b, c, 0, 0, 0);
}
// async global->LDS, 16B/lane; lds must be wave-uniform base (HW adds lane*16)
__device__ __forceinline__ void async16(void* lds, const void* g) {
    __builtin_amdgcn_global_load_lds(
        (const __attribute__((address_space(1))) u32*)g,
        (__attribute__((address_space(3))) u32*)lds, 16, 0, 0);
}
// v_dot2_f32_f16: acc += a.x*b.x + a.y*b.y (f16 inputs, f32 acc)
__device__ __forceinline__ float fdot2_(u32 a, u32 b, float c) {
#if __has_builtin(__builtin_amdgcn_fdot2)
    return __builtin_amdgcn_fdot2(__builtin_bit_cast(h16x2, a),
                                  __builtin_bit_cast(h16x2, b), c, false);
#else
    float d;
    asm volatile("v_dot2_f32_f16 %0, %1, %2, %3"
                 : "=v"(d) : "v"(a), "v"(b), "v"(c));
    return d;
#endif
}
// dot of f16x8 P-fragment with f16x8 flag word (as uint4), f32 accumulate
__device__ __forceinline__ float dot8(f16x8 p, uint4 f, float acc) {
    uint4 pw = __builtin_bit_cast(uint4, p);
    acc = fdot2_(pw.x, f.x, acc);
    acc = fdot2_(pw.y, f.y, acc);
    acc = fdot2_(pw.z, f.z, acc);
    acc = fdot2_(pw.w, f.w, acc);
    return acc;
}

// ---------------------------------------------------------------------------
// Packed fp16 format: per 64-elem logical row, a 128B record of 8 x 16B
// blocks XOR-swizzled: element e of row r lives at ((e>>3)^(r&7))*16+(e&7)*2.
//
// KEY PERMUTATION (attn): within each 32-key span, key kt*16+q*4+r is
// stored at slot q*8+kt*4+r.  With V rows and l-flags permuted by this
// sigma, the MFMA C-layout P values (key=quad*4+r per kt) ARE the PV
// B-operand fragment (k-slot quad*8+j) in-register -> P never touches LDS.
// ---------------------------------------------------------------------------

// x [4096][1024] fp32 -> Xp [m][kc=16][128B]; emits slot-permuted fp16 flags
__global__ __launch_bounds__(256) void pack_x(const float* __restrict__ X,
                                              uchar* __restrict__ P,
                                              const int* __restrict__ M,
                                              _Float16* __restrict__ FM16)
{
    int id = blockIdx.x * 256 + threadIdx.x;       // 4096*128
    int m = id >> 7, g = id & 127;
    int kc = g >> 3, b = g & 7;
    float v[8];
    *(float4*)&v[0] = *(const float4*)&X[(size_t)m * HDIM + kc * 64 + b * 8];
    *(float4*)&v[4] = *(const float4*)&X[(size_t)m * HDIM + kc * 64 + b * 8 + 4];
    __align__(16) _Float16 h[8];
    #pragma unroll
    for (int i = 0; i < 8; i++) h[i] = (_Float16)v[i];
    size_t base = ((size_t)(m * 16 + kc)) * 128 + (size_t)((b ^ (m & 7)) * 16);
    *(uint4*)(P + base) = *(const uint4*)h;
    if (id < S_LEN) {
        int c = id >> 7, k128 = id & 127;
        int w = k128 >> 5, k32 = k128 & 31;
        int q = (k32 >> 2) & 3, kt = k32 >> 4, r = k32 & 3;
        FM16[c * 128 + w * 32 + q * 8 + kt * 4 + r] =
            (_Float16)((M[id] == 0) ? 0.0f : 1.0f);
    }
}

// All 4 weight matrices [1024 k][1024 n] fp32 -> fp16 B^T rows [n][kc=16][128B]
__global__ __launch_bounds__(256) void pack_w4(
    const float* __restrict__ W0, const float* __restrict__ W1,
    const float* __restrict__ W2, const float* __restrict__ W3,
    uchar* __restrict__ P)
{
    int id = blockIdx.x * 256 + threadIdx.x;       // 4*128*1024
    int wsel = id >> 17;
    int lid  = id & 131071;
    int g = lid >> 10, n = lid & 1023;
    int kc = g >> 3, b = g & 7;
    const float* W = (wsel == 0) ? W0 : (wsel == 1) ? W1 : (wsel == 2) ? W2 : W3;
    uchar* dst = P + (size_t)wsel * 2097152;
    float v[8];
    #pragma unroll
    for (int j = 0; j < 8; j++)
        v[j] = W[(size_t)(kc * 64 + b * 8 + j) * HDIM + n];
    __align__(16) _Float16 h[8];
    #pragma unroll
    for (int i = 0; i < 8; i++) h[i] = (_Float16)v[i];
    size_t base = ((size_t)(n * 16 + kc)) * 128 + (size_t)((b ^ (n & 7)) * 16);
    *(uint4*)(dst + base) = *(const uint4*)h;
}

// ---------------------------------------------------------------------------
// Single-fp16 MFMA GEMM, single-barrier double-buffered (unchanged).
// ---------------------------------------------------------------------------
__global__ __launch_bounds__(256) void gemm_f16(
    const uchar* __restrict__ Ap, const uchar* __restrict__ Bp,
    float* __restrict__ C, int head_major)
{
    __shared__ __align__(16) uchar AB[65536];
    const int t = threadIdx.x, lane = t & 63, w = t >> 6;
    const int quad = lane >> 4, l15 = lane & 15, x7 = l15 & 7;
    const int m0 = blockIdx.y * 128, n0 = blockIdx.x * 128;
    const int wm = (w >> 1) * 64, wn = (w & 1) * 64;

    f32x4 acc[4][4];
    const f32x4 zero4 = {0.0f, 0.0f, 0.0f, 0.0f};
    #pragma unroll
    for (int mt = 0; mt < 4; mt++)
        #pragma unroll
        for (int nt = 0; nt < 4; nt++) acc[mt][nt] = zero4;

    #pragma unroll
    for (int i = 0; i < 4; i++) {
        int idx = i * 256 + t;
        int row = idx >> 3, blk = idx & 7;
        int ldso = (idx & ~63) * 16;
        async16(AB + ldso,         Ap + ((size_t)((m0 + row) * 16 + 0)) * 128 + blk * 16);
        async16(AB + 16384 + ldso, Bp + ((size_t)((n0 + row) * 16 + 0)) * 128 + blk * 16);
    }

    for (int kc = 0; kc < 16; kc++) {
        uchar* As = AB + (kc & 1) * 32768;
        uchar* Bs = As + 16384;
        __syncthreads();
        if (kc + 1 < 16) {
            uchar* An = AB + ((kc + 1) & 1) * 32768;
            #pragma unroll
            for (int i = 0; i < 4; i++) {
                int idx = i * 256 + t;
                int row = idx >> 3, blk = idx & 7;
                int ldso = (idx & ~63) * 16;
                async16(An + ldso,
                        Ap + ((size_t)((m0 + row) * 16 + kc + 1)) * 128 + blk * 16);
                async16(An + 16384 + ldso,
                        Bp + ((size_t)((n0 + row) * 16 + kc + 1)) * 128 + blk * 16);
            }
        }
        #pragma unroll
        for (int ks = 0; ks < 2; ks++) {
            const int phys = ((ks * 4 + quad) ^ x7) * 16;
            f16x8 ah[4];
            #pragma unroll
            for (int mt = 0; mt < 4; mt++)
                ah[mt] = *(const f16x8*)(As + (size_t)(wm + mt * 16 + l15) * 128 + phys);
            #pragma unroll
            for (int nt = 0; nt < 4; nt++) {
                f16x8 bh = *(const f16x8*)(Bs + (size_t)(wn + nt * 16 + l15) * 128 + phys);
                #pragma unroll
                for (int mt = 0; mt < 4; mt++)
                    acc[mt][nt] = mfma16h(ah[mt], bh, acc[mt][nt]);
            }
        }
    }

    #pragma unroll
    for (int mt = 0; mt < 4; mt++)
        #pragma unroll
        for (int nt = 0; nt < 4; nt++)
            #pragma unroll
            for (int r = 0; r < 4; r++) {
                int m = m0 + wm + mt * 16 + quad * 4 + r;
                int n = n0 + wn + nt * 16 + l15;
                float val = acc[mt][nt][r];
                if (head_major) {
                    int hh = n >> 6, d = n & 63;
                    C[((size_t)hh * S_LEN + m) * HD + d] = val;
                } else {
                    C[(size_t)m * HDIM + n] = val;
                }
            }
}

// ---------------------------------------------------------------------------
// RoPE + pack -> fp16 single, 128B rows (Q scaled 0.125*log2e)
// ---------------------------------------------------------------------------
__global__ __launch_bounds__(256) void rope_pack(const float* __restrict__ QKVf,
                                                 uchar* __restrict__ Qg,
                                                 uchar* __restrict__ Kg)
{
    int id = blockIdx.x * 256 + threadIdx.x;   // 2*16*4096*8
    int g  = id & 7;
    int s  = (id >> 3) & (S_LEN - 1);
    int hb = id >> 15;
    const float* src = QKVf + (size_t)hb * (S_LEN * HD) + (size_t)s * HD + g * 8;
    float v[8];
    *(float4*)&v[0] = *(const float4*)&src[0];
    *(float4*)&v[4] = *(const float4*)&src[4];

    const float L32 = 13.287712379549449f / 32.0f;
    float out[8];
    #pragma unroll
    for (int u = 0; u < 4; u++) {
        int de = g * 8 + 2 * u;
        float ae = (float)s * __builtin_amdgcn_exp2f(-(float)(de & 31) * L32);
        float ao = (float)s * __builtin_amdgcn_exp2f(-(float)((de + 1) & 31) * L32);
        float ce = __cosf(ae), se = __sinf(ae);
        float co = __cosf(ao), so = __sinf(ao);
        float xe = v[2 * u], xo = v[2 * u + 1];
        out[2 * u]     = xe * ce - xo * se;
        out[2 * u + 1] = xo * co + xe * so;
    }
    const bool isQ = hb < 16;
    const float scale = isQ ? 0.18033688011112042f : 1.0f;  // 0.125*log2e
    __align__(16) _Float16 h[8];
    #pragma unroll
    for (int i = 0; i < 8; i++) h[i] = (_Float16)(out[i] * scale);
    uchar* dst = (isQ ? Qg : Kg);
    size_t base = ((size_t)((hb & 15) * S_LEN + s)) * 128 + (size_t)((g ^ (s & 7)) * 16);
    *(uint4*)(dst + base) = *(const uint4*)h;
}

// ---------------------------------------------------------------------------
// V pack: fp32 head-major -> fp16 transposed 16KB tiles [head][32][64d][slots],
// key rows SLOT-PERMUTED (sigma: key kt*16+q*4+r -> slot q*8+kt*4+r within
// each 32-key span). Masked keys zeroed.
// ---------------------------------------------------------------------------
__global__ __launch_bounds__(256) void v_pack(const float* __restrict__ Vf,
                                              const int* __restrict__ M,
                                              uchar* __restrict__ Vg)
{
    int id = blockIdx.x * 256 + threadIdx.x;   // 16*32*16*64
    int d    = id & 63;
    int kg   = (id >> 6) & 15;
    int kc2  = (id >> 10) & 31;
    int head = id >> 15;
    __align__(16) _Float16 hv[8];
    #pragma unroll
    for (int j = 0; j < 8; j++) {
        int key = kc2 * 128 + kg * 8 + j;
        float x = Vf[(size_t)head * (S_LEN * HD) + (size_t)key * HD + d];
        hv[j] = (M[key] == 0) ? (_Float16)0.0f : (_Float16)x;
    }
    // keys kg*8 .. kg*8+7 -> two 4-key granules at permuted slots
    int wv  = kg >> 2;               // span
    int kgm = kg & 3;
    int kt  = kgm >> 1;
    int qA  = (kgm * 2) & 3;
    int qB  = (kgm * 2 + 1) & 3;
    int slotA = wv * 32 + qA * 8 + kt * 4;   // granule j=0..3
    int slotB = wv * 32 + qB * 8 + kt * 4;   // granule j=4..7
    size_t row = ((size_t)(head * 32 + kc2)) * 16384 + (size_t)d * 256;
    *(ushort4*)(Vg + row + (size_t)(((slotA >> 3) ^ (d & 7)) * 16 + (slotA & 7) * 2))
        = *(const ushort4*)&hv[0];
    *(ushort4*)(Vg + row + (size_t)(((slotB >> 3) ^ (d & 7)) * 16 + (slotB & 7) * 2))
        = *(const ushort4*)&hv[4];
}

// ---------------------------------------------------------------------------
// attn9 R14: barrier-free wave pipeline, 4 waves/SIMD.
//
// R12/R13 lesson: 64q x 64d per wave = 64 AGPR o-acc -> total ~160-184 regs
// -> 2 waves/SIMD max, forcing the cap spills.  Repartition: wave (qh,kh) =
// 32q x 64d x 2048 keys (64 steps x 32 keys).  o = 32 AGPR, qf = 16 VGPR;
// peak live ~105 regs -> __launch_bounds__(256,4) legal without spill.
// Grid 1024 = exactly 4 blocks/CU x 256 CUs.  Cost: K/V DMA'd twice per
// block (qh pair) -> ~2.1GB L2 reads; accepted, measured this round.
//
// Single flag reg, reloaded 1 step ahead.  vmcnt: steady top 5 (retire K(c)),
// mid 4 (retire V(c)+flag(c), keep K(c+1) in flight); peel step0 (4,4),
// step63 (5,0).  P stays in registers (sigma-permuted V/flags as before).
// TRIPWIRE: WRITE_SIZE > 9MB = spill -> revert to R1 structure.
// ---------------------------------------------------------------------------
#define ISSUE_K(CC)                                                            \
  {                                                                            \
    const uchar* ks_ = kgb + (size_t)(CC) * 4096;                              \
    async16(KB,        ks_ + l16);                                             \
    async16(KB + 1024, ks_ + 1024 + l16);                                      \
    async16(KB + 2048, ks_ + 2048 + l16);                                      \
    async16(KB + 3072, ks_ + 3072 + l16);                                      \
  }
#define ISSUE_V(CC)                                                            \
  {                                                                            \
    const uchar* vs_ = vgb + (size_t)((CC) >> 2) * 16384;                      \
    int vph_  = ((((CC) & 3) << 2) | va0) ^ vb0;                               \
    int voff_ = vbase + vph_ * 16;                                             \
    async16(VB,        vs_ + voff_);                                           \
    async16(VB + 1024, vs_ + 4096 + voff_);                                    \
    async16(VB + 2048, vs_ + 8192 + voff_);                                    \
    async16(VB + 3072, vs_ + 12288 + voff_);                                   \
  }

#define ATTN_STEP(CC, TOPC, MIDC)                                              \
  {                                                                            \
    asm volatile("s_waitcnt vmcnt(" TOPC ")" ::: "memory");                    \
    const int ph0_ = (quad ^ x7) * 16;                                         \
    const int ph1_ = ((4 + quad) ^ x7) * 16;                                   \
    f16x8 ka_ = *(const f16x8*)(KB + (size_t)l15 * 128 + ph0_);                \
    f16x8 kb_ = *(const f16x8*)(KB + (size_t)(16 + l15) * 128 + ph0_);         \
    f16x8 kc_ = *(const f16x8*)(KB + (size_t)l15 * 128 + ph1_);                \
    f16x8 kd_ = *(const f16x8*)(KB + (size_t)(16 + l15) * 128 + ph1_);         \
    asm volatile("s_waitcnt lgkmcnt(0)" ::: "memory");                         \
    if ((CC) + 1 < 64) ISSUE_K((CC) + 1);                                      \
    f16x8 pb[2];                                                               \
    _Pragma("unroll")                                                          \
    for (int qt = 0; qt < 2; qt++) {                                           \
      f32x4 s0 = mfma16h(ka_, qf[qt][0], zero4);                               \
      s0 = mfma16h(kc_, qf[qt][1], s0);                                        \
      f32x4 s1 = mfma16h(kb_, qf[qt][0], zero4);                               \
      s1 = mfma16h(kd_, qf[qt][1], s1);                                        \
      h16x2 c01 = __builtin_amdgcn_cvt_pkrtz(                                  \
          __builtin_amdgcn_exp2f(s0[0]), __builtin_amdgcn_exp2f(s0[1]));       \
      h16x2 c23 = __builtin_amdgcn_cvt_pkrtz(                                  \
          __builtin_amdgcn_exp2f(s0[2]), __builtin_amdgcn_exp2f(s0[3]));       \
      h16x2 c45 = __builtin_amdgcn_cvt_pkrtz(                                  \
          __builtin_amdgcn_exp2f(s1[0]), __builtin_amdgcn_exp2f(s1[1]));       \
      h16x2 c67 = __builtin_amdgcn_cvt_pkrtz(                                  \
          __builtin_amdgcn_exp2f(s1[2]), __builtin_amdgcn_exp2f(s1[3]));       \
      uint4 pw;                                                                \
      pw.x = __builtin_bit_cast(u32, c01);                                     \
      pw.y = __builtin_bit_cast(u32, c23);                                     \
      pw.z = __builtin_bit_cast(u32, c45);                                     \
      pw.w = __builtin_bit_cast(u32, c67);                                     \
      pb[qt] = __builtin_bit_cast(f16x8, pw);                                  \
    }                                                                          \
    asm volatile("s_waitcnt vmcnt(" MIDC ")" ::: "memory");                    \
    _Pragma("unroll")                                                          \
    for (int dt = 0; dt < 4; dt++) {                                           \
      f16x8 va = *(const f16x8*)(VB + (size_t)(dt * 16 + l15) * 64 + vrd);     \
      o[dt][0] = mfma16h(va, pb[0], o[dt][0]);                                 \
      o[dt][1] = mfma16h(va, pb[1], o[dt][1]);                                 \
    }                                                                          \
    lacc[0] = dot8(pb[0], flag, lacc[0]);                                      \
    lacc[1] = dot8(pb[1], flag, lacc[1]);                                      \
    asm volatile("s_waitcnt lgkmcnt(0)" ::: "memory");                         \
    if ((CC) + 1 < 64) {                                                       \
      ISSUE_V((CC) + 1);                                                       \
      flag = *(const uint4*)(fmw + (size_t)((CC) + 1) * 64);                   \
    }                                                                          \
  }

__global__ __launch_bounds__(256, 4) void attn9(
    const uchar* __restrict__ Qg, const uchar* __restrict__ Kg,
    const uchar* __restrict__ Vg, const uchar* __restrict__ fm16,
    uchar* __restrict__ CTXp)
{
    __shared__ __align__(16) uchar arena[32768];   // 4 waves x [K|V] 4KB each
    float* Os   = (float*)arena;                   // post-loop overlays
    float* Lsh  = (float*)(arena + 18432);         // [4][32]
    float* Lfin = (float*)(arena + 18944);         // [64]

    const int t    = threadIdx.x;
    const int lane = t & 63;
    const int w    = t >> 6;
    const int quad = lane >> 4;
    const int l15  = lane & 15;
    const int x7   = l15 & 7;
    const int hh   = blockIdx.y;
    const int m0   = blockIdx.x * 64;
    const int qh   = w >> 1;              // 0/1: q-half
    const int kh   = w & 1;               // 0/1: key-half

    const uchar* qgb = Qg + (size_t)hh * (S_LEN * 128);
    const uchar* kgb = Kg + (size_t)hh * (S_LEN * 128) + (size_t)kh * 262144;
    const uchar* vgb = Vg + (size_t)hh * (32 * 16384) + (size_t)kh * 262144;
    const uchar* fmw = fm16 + (size_t)kh * 4096 + quad * 16;

    uchar* WB = arena + w * 8192;
    uchar* KB = WB;
    uchar* VB = WB + 4096;

    const int l16   = lane * 16;
    const int va0   = (lane & 3) ^ ((lane >> 2) & 3);
    const int vb0   = (lane >> 2) & 7;
    const int vbase = (lane >> 2) * 256;
    const int vrd   = (quad ^ (l15 & 3)) * 16;

    // ---- Q fragments -> registers, once (32 q rows for this wave) ----
    f16x8 qf[2][2];
    #pragma unroll
    for (int qt = 0; qt < 2; qt++)
        #pragma unroll
        for (int ks = 0; ks < 2; ks++)
            qf[qt][ks] = *(const f16x8*)(qgb +
                (size_t)(m0 + qh * 32 + qt * 16 + l15) * 128 +
                (size_t)(((ks * 4 + quad) ^ x7) * 16));

    f32x4 o[4][2];
    float lacc[2] = {0.0f, 0.0f};
    const f32x4 zero4 = {0.0f, 0.0f, 0.0f, 0.0f};
    #pragma unroll
    for (int dt = 0; dt < 4; dt++) {
        o[dt][0] = zero4;
        o[dt][1] = zero4;
    }

    // ---- prologue: flag(0) then DMA issues (count-robust either order) ----
    uint4 flag = *(const uint4*)(fmw);
    asm volatile("" ::: "memory");
    ISSUE_K(0);
    ISSUE_V(0);

    ATTN_STEP(0, "4", "4");
    for (int c = 1; c < 63; ++c)
        ATTN_STEP(c, "5", "4");
    ATTN_STEP(63, "5", "0");

    // ---- l finalize: cross-quad reduce in-register, then cross-kh ----
    #pragma unroll
    for (int qt = 0; qt < 2; qt++) {
        float v = lacc[qt];
        v += __shfl_xor(v, 16);
        v += __shfl_xor(v, 32);
        lacc[qt] = v;
    }
    __syncthreads();                 // all waves done; arena reusable
    if (quad == 0) {
        Lsh[w * 32 + l15]      = lacc[0];
        Lsh[w * 32 + 16 + l15] = lacc[1];
    }
    __syncthreads();
    if (t < 64) {
        int qhh = t >> 5, ql = t & 31;
        Lfin[t] = Lsh[(qhh * 2) * 32 + ql] + Lsh[(qhh * 2 + 1) * 32 + ql];
    }
    __syncthreads();

    // ---- o merge: kh=0 waves write, kh=1 waves add (disjoint q-halves) ----
    if (kh == 0) {
        #pragma unroll
        for (int dt = 0; dt < 4; dt++)
            #pragma unroll
            for (int qt = 0; qt < 2; qt++)
                #pragma unroll
                for (int r = 0; r < 4; r++) {
                    int q = qh * 32 + qt * 16 + l15;
                    int d = dt * 16 + quad * 4 + r;
                    Os[q * 68 + d] = o[dt][qt][r];
                }
    }
    __syncthreads();
    if (kh == 1) {
        #pragma unroll
        for (int dt = 0; dt < 4; dt++)
            #pragma unroll
            for (int qt = 0; qt < 2; qt++)
                #pragma unroll
                for (int r = 0; r < 4; r++) {
                    int q = qh * 32 + qt * 16 + l15;
                    int d = dt * 16 + quad * 4 + r;
                    Os[q * 68 + d] += o[dt][qt][r];
                }
    }
    __syncthreads();

    // ---- epilogue: ctx packed fp16, kc = head (feeds Wo GEMM) ----
    #pragma unroll
    for (int i = 0; i < 4; i++) {
        int idx = t + 256 * i;
        int q   = idx >> 4;
        int c4  = (idx & 15) * 4;
        float inv = 1.0f / Lfin[q];
        float4 v = *(const float4*)&Os[q * 68 + c4];
        int m = m0 + q;
        __align__(8) _Float16 h[4];
        h[0] = (_Float16)(v.x * inv);
        h[1] = (_Float16)(v.y * inv);
        h[2] = (_Float16)(v.z * inv);
        h[3] = (_Float16)(v.w * inv);
        size_t base = ((size_t)(m * 16 + hh)) * 128 +
                      (size_t)((((c4 >> 3) ^ (m & 7))) * 16) + (c4 & 7) * 2;
        *(ushort4*)(CTXp + base) = *(const ushort4*)h;
    }
}

// ---------------------------------------------------------------------------
extern "C" void kernel_launch(void* const* d_in, const int* in_sizes, int n_in,
                              void* d_out, int out_size, void* d_ws, size_t ws_size,
                              hipStream_t stream)
{
    const float* x   = (const float*)d_in[0];
    const float* Wq  = (const float*)d_in[1];
    const float* Wk  = (const float*)d_in[2];
    const float* Wv  = (const float*)d_in[3];
    const float* Wo  = (const float*)d_in[4];
    const int* amask = (const int*)d_in[5];
    float* out = (float*)d_out;
    float* ws  = (float*)d_ws;

    // byte-offset workspace map:
    //   QKVf  fp32 [48][4096][64]   bytes [0, 50331648)
    //   Xp    fp16 packed x (8.4MB) bytes [50331648, 58720256)  later = Qg
    //   Wt4   fp16 packed W^T x4    bytes [58720256, 67108864)  (2MB each)
    //   Vg    fp16 V tiles (8.4MB)  bytes [67108864, 75497472)
    //   Fm16  fp16 flags (8KB)      bytes [75497472, 75505664)
    //   Kg    = bytes [33554432, 41943040)   (over Vf, dead after v_pack)
    //   CTXp  = bytes [0, 8388608)           (over Qf, dead after rope)
    float* QKVf = ws;
    uchar* Xp   = (uchar*)ws + 50331648;
    uchar* Wt4  = (uchar*)ws + 58720256;
    uchar* Vg   = (uchar*)ws + 67108864;
    _Float16* Fm16 = (_Float16*)((uchar*)ws + 75497472);
    uchar* Qg   = Xp;
    uchar* Kg   = (uchar*)ws + 33554432;
    uchar* CTXp = (uchar*)ws;

    dim3 blk(256);

    pack_x<<<2048, blk, 0, stream>>>(x, Xp, amask, Fm16);
    pack_w4<<<2048, blk, 0, stream>>>(Wq, Wk, Wv, Wo, Wt4);

    // fused QKV projection: N = 3072, head-major out (heads 0..47)
    gemm_f16<<<dim3(24, 32), blk, 0, stream>>>(Xp, Wt4, QKVf, 1);

    // V pack BEFORE rope (Kg aliases Vf region); masked rows zeroed, slots permuted
    v_pack<<<2048, blk, 0, stream>>>(QKVf + 8388608, amask, Vg);
    rope_pack<<<4096, blk, 0, stream>>>(QKVf, Qg, Kg);

    attn9<<<dim3(S_LEN / 64, NHEADS), blk, 0, stream>>>(Qg, Kg, Vg,
                                                        (const uchar*)Fm16, CTXp);

    // output projection: N = 1024, row-major out (Wo at Wt4 + 3*2MB)
    gemm_f16<<<dim3(8, 32), blk, 0, stream>>>(CTXp, Wt4 + 6291456, out, 0);
}

// Round 5
// 248.395 us; speedup vs baseline: 1.0534x; 1.0534x over previous
//
#include <hip/hip_runtime.h>
#include <cstdint>
#include <cstddef>

// Problem constants (B=1, S=4096, H=1024, 16 heads x 64)
#define S_LEN 4096
#define NHEADS 16
#define HD 64
#define HDIM 1024

typedef _Float16 f16x8 __attribute__((ext_vector_type(8)));
typedef _Float16 f16x4 __attribute__((ext_vector_type(4)));
typedef __fp16 h16x2 __attribute__((ext_vector_type(2)));   // cvt_pkrtz native
typedef float f32x4 __attribute__((ext_vector_type(4)));
typedef unsigned char uchar;
typedef unsigned int u32;

__device__ __forceinline__ f32x4 mfma16h(f16x8 a, f16x8 b, f32x4 c) {
    return __builtin_amdgcn_mfma_f32_16x16x32_f16(a, b, c, 0, 0, 0);
}
// async global->LDS, 16B/lane; lds must be wave-uniform base (HW adds lane*16)
__device__ __forceinline__ void async16(void* lds, const void* g) {
    __builtin_amdgcn_global_load_lds(
        (const __attribute__((address_space(1))) u32*)g,
        (__attribute__((address_space(3))) u32*)lds, 16, 0, 0);
}
// v_dot2_f32_f16: acc += a.x*b.x + a.y*b.y (f16 inputs, f32 acc)
__device__ __forceinline__ float fdot2_(u32 a, u32 b, float c) {
#if __has_builtin(__builtin_amdgcn_fdot2)
    return __builtin_amdgcn_fdot2(__builtin_bit_cast(h16x2, a),
                                  __builtin_bit_cast(h16x2, b), c, false);
#else
    float d;
    asm volatile("v_dot2_f32_f16 %0, %1, %2, %3"
                 : "=v"(d) : "v"(a), "v"(b), "v"(c));
    return d;
#endif
}
// dot of f16x8 P-fragment with f16x8 flag word (as uint4), f32 accumulate
__device__ __forceinline__ float dot8(f16x8 p, uint4 f, float acc) {
    uint4 pw = __builtin_bit_cast(uint4, p);
    acc = fdot2_(pw.x, f.x, acc);
    acc = fdot2_(pw.y, f.y, acc);
    acc = fdot2_(pw.z, f.z, acc);
    acc = fdot2_(pw.w, f.w, acc);
    return acc;
}

// ---------------------------------------------------------------------------
// Packed fp16 format: per 64-elem logical row, a 128B record of 8 x 16B
// blocks XOR-swizzled: element e of row r lives at ((e>>3)^(r&7))*16+(e&7)*2.
//
// KEY PERMUTATION (attn): within each wave's 32-key slice, key kt*16+q*4+r
// is stored at slot q*8+kt*4+r.  With V rows and l-flags permuted by this
// sigma, the MFMA C-layout P values (key=quad*4+r per kt) ARE the PV
// B-operand fragment (k-slot quad*8+j) in-register -> P never touches LDS.
// ---------------------------------------------------------------------------

// x [4096][1024] fp32 -> Xp [m][kc=16][128B]; emits slot-permuted fp16 flags
__global__ __launch_bounds__(256) void pack_x(const float* __restrict__ X,
                                              uchar* __restrict__ P,
                                              const int* __restrict__ M,
                                              _Float16* __restrict__ FM16)
{
    int id = blockIdx.x * 256 + threadIdx.x;       // 4096*128
    int m = id >> 7, g = id & 127;
    int kc = g >> 3, b = g & 7;
    float v[8];
    *(float4*)&v[0] = *(const float4*)&X[(size_t)m * HDIM + kc * 64 + b * 8];
    *(float4*)&v[4] = *(const float4*)&X[(size_t)m * HDIM + kc * 64 + b * 8 + 4];
    __align__(16) _Float16 h[8];
    #pragma unroll
    for (int i = 0; i < 8; i++) h[i] = (_Float16)v[i];
    size_t base = ((size_t)(m * 16 + kc)) * 128 + (size_t)((b ^ (m & 7)) * 16);
    *(uint4*)(P + base) = *(const uint4*)h;
    if (id < S_LEN) {
        int c = id >> 7, k128 = id & 127;
        int w = k128 >> 5, k32 = k128 & 31;
        int q = (k32 >> 2) & 3, kt = k32 >> 4, r = k32 & 3;
        FM16[c * 128 + w * 32 + q * 8 + kt * 4 + r] =
            (_Float16)((M[id] == 0) ? 0.0f : 1.0f);
    }
}

// All 4 weight matrices [1024 k][1024 n] fp32 -> fp16 B^T rows [n][kc=16][128B]
__global__ __launch_bounds__(256) void pack_w4(
    const float* __restrict__ W0, const float* __restrict__ W1,
    const float* __restrict__ W2, const float* __restrict__ W3,
    uchar* __restrict__ P)
{
    int id = blockIdx.x * 256 + threadIdx.x;       // 4*128*1024
    int wsel = id >> 17;
    int lid  = id & 131071;
    int g = lid >> 10, n = lid & 1023;
    int kc = g >> 3, b = g & 7;
    const float* W = (wsel == 0) ? W0 : (wsel == 1) ? W1 : (wsel == 2) ? W2 : W3;
    uchar* dst = P + (size_t)wsel * 2097152;
    float v[8];
    #pragma unroll
    for (int j = 0; j < 8; j++)
        v[j] = W[(size_t)(kc * 64 + b * 8 + j) * HDIM + n];
    __align__(16) _Float16 h[8];
    #pragma unroll
    for (int i = 0; i < 8; i++) h[i] = (_Float16)v[i];
    size_t base = ((size_t)(n * 16 + kc)) * 128 + (size_t)((b ^ (n & 7)) * 16);
    *(uint4*)(dst + base) = *(const uint4*)h;
}

// ---------------------------------------------------------------------------
// Single-fp16 MFMA GEMM, single-barrier double-buffered (unchanged).
// ---------------------------------------------------------------------------
__global__ __launch_bounds__(256) void gemm_f16(
    const uchar* __restrict__ Ap, const uchar* __restrict__ Bp,
    float* __restrict__ C, int head_major)
{
    __shared__ __align__(16) uchar AB[65536];
    const int t = threadIdx.x, lane = t & 63, w = t >> 6;
    const int quad = lane >> 4, l15 = lane & 15, x7 = l15 & 7;
    const int m0 = blockIdx.y * 128, n0 = blockIdx.x * 128;
    const int wm = (w >> 1) * 64, wn = (w & 1) * 64;

    f32x4 acc[4][4];
    const f32x4 zero4 = {0.0f, 0.0f, 0.0f, 0.0f};
    #pragma unroll
    for (int mt = 0; mt < 4; mt++)
        #pragma unroll
        for (int nt = 0; nt < 4; nt++) acc[mt][nt] = zero4;

    #pragma unroll
    for (int i = 0; i < 4; i++) {
        int idx = i * 256 + t;
        int row = idx >> 3, blk = idx & 7;
        int ldso = (idx & ~63) * 16;
        async16(AB + ldso,         Ap + ((size_t)((m0 + row) * 16 + 0)) * 128 + blk * 16);
        async16(AB + 16384 + ldso, Bp + ((size_t)((n0 + row) * 16 + 0)) * 128 + blk * 16);
    }

    for (int kc = 0; kc < 16; kc++) {
        uchar* As = AB + (kc & 1) * 32768;
        uchar* Bs = As + 16384;
        __syncthreads();
        if (kc + 1 < 16) {
            uchar* An = AB + ((kc + 1) & 1) * 32768;
            #pragma unroll
            for (int i = 0; i < 4; i++) {
                int idx = i * 256 + t;
                int row = idx >> 3, blk = idx & 7;
                int ldso = (idx & ~63) * 16;
                async16(An + ldso,
                        Ap + ((size_t)((m0 + row) * 16 + kc + 1)) * 128 + blk * 16);
                async16(An + 16384 + ldso,
                        Bp + ((size_t)((n0 + row) * 16 + kc + 1)) * 128 + blk * 16);
            }
        }
        #pragma unroll
        for (int ks = 0; ks < 2; ks++) {
            const int phys = ((ks * 4 + quad) ^ x7) * 16;
            f16x8 ah[4];
            #pragma unroll
            for (int mt = 0; mt < 4; mt++)
                ah[mt] = *(const f16x8*)(As + (size_t)(wm + mt * 16 + l15) * 128 + phys);
            #pragma unroll
            for (int nt = 0; nt < 4; nt++) {
                f16x8 bh = *(const f16x8*)(Bs + (size_t)(wn + nt * 16 + l15) * 128 + phys);
                #pragma unroll
                for (int mt = 0; mt < 4; mt++)
                    acc[mt][nt] = mfma16h(ah[mt], bh, acc[mt][nt]);
            }
        }
    }

    #pragma unroll
    for (int mt = 0; mt < 4; mt++)
        #pragma unroll
        for (int nt = 0; nt < 4; nt++)
            #pragma unroll
            for (int r = 0; r < 4; r++) {
                int m = m0 + wm + mt * 16 + quad * 4 + r;
                int n = n0 + wn + nt * 16 + l15;
                float val = acc[mt][nt][r];
                if (head_major) {
                    int hh = n >> 6, d = n & 63;
                    C[((size_t)hh * S_LEN + m) * HD + d] = val;
                } else {
                    C[(size_t)m * HDIM + n] = val;
                }
            }
}

// ---------------------------------------------------------------------------
// RoPE + pack -> fp16 single, 128B rows (Q scaled 0.125*log2e)
// ---------------------------------------------------------------------------
__global__ __launch_bounds__(256) void rope_pack(const float* __restrict__ QKVf,
                                                 uchar* __restrict__ Qg,
                                                 uchar* __restrict__ Kg)
{
    int id = blockIdx.x * 256 + threadIdx.x;   // 2*16*4096*8
    int g  = id & 7;
    int s  = (id >> 3) & (S_LEN - 1);
    int hb = id >> 15;
    const float* src = QKVf + (size_t)hb * (S_LEN * HD) + (size_t)s * HD + g * 8;
    float v[8];
    *(float4*)&v[0] = *(const float4*)&src[0];
    *(float4*)&v[4] = *(const float4*)&src[4];

    const float L32 = 13.287712379549449f / 32.0f;
    float out[8];
    #pragma unroll
    for (int u = 0; u < 4; u++) {
        int de = g * 8 + 2 * u;
        float ae = (float)s * __builtin_amdgcn_exp2f(-(float)(de & 31) * L32);
        float ao = (float)s * __builtin_amdgcn_exp2f(-(float)((de + 1) & 31) * L32);
        float ce = __cosf(ae), se = __sinf(ae);
        float co = __cosf(ao), so = __sinf(ao);
        float xe = v[2 * u], xo = v[2 * u + 1];
        out[2 * u]     = xe * ce - xo * se;
        out[2 * u + 1] = xo * co + xe * so;
    }
    const bool isQ = hb < 16;
    const float scale = isQ ? 0.18033688011112042f : 1.0f;  // 0.125*log2e
    __align__(16) _Float16 h[8];
    #pragma unroll
    for (int i = 0; i < 8; i++) h[i] = (_Float16)(out[i] * scale);
    uchar* dst = (isQ ? Qg : Kg);
    size_t base = ((size_t)((hb & 15) * S_LEN + s)) * 128 + (size_t)((g ^ (s & 7)) * 16);
    *(uint4*)(dst + base) = *(const uint4*)h;
}

// ---------------------------------------------------------------------------
// V pack: fp32 head-major -> fp16 transposed 16KB tiles [head][32][64d][slots],
// key rows SLOT-PERMUTED (sigma: key kt*16+q*4+r -> slot q*8+kt*4+r within
// each 32-key wave span). Masked keys zeroed.
// ---------------------------------------------------------------------------
__global__ __launch_bounds__(256) void v_pack(const float* __restrict__ Vf,
                                              const int* __restrict__ M,
                                              uchar* __restrict__ Vg)
{
    int id = blockIdx.x * 256 + threadIdx.x;   // 16*32*16*64
    int d    = id & 63;
    int kg   = (id >> 6) & 15;
    int kc2  = (id >> 10) & 31;
    int head = id >> 15;
    __align__(16) _Float16 hv[8];
    #pragma unroll
    for (int j = 0; j < 8; j++) {
        int key = kc2 * 128 + kg * 8 + j;
        float x = Vf[(size_t)head * (S_LEN * HD) + (size_t)key * HD + d];
        hv[j] = (M[key] == 0) ? (_Float16)0.0f : (_Float16)x;
    }
    // keys kg*8 .. kg*8+7 -> two 4-key granules at permuted slots
    int wv  = kg >> 2;               // wave slice
    int kgm = kg & 3;
    int kt  = kgm >> 1;
    int qA  = (kgm * 2) & 3;
    int qB  = (kgm * 2 + 1) & 3;
    int slotA = wv * 32 + qA * 8 + kt * 4;   // granule j=0..3
    int slotB = wv * 32 + qB * 8 + kt * 4;   // granule j=4..7
    size_t row = ((size_t)(head * 32 + kc2)) * 16384 + (size_t)d * 256;
    *(ushort4*)(Vg + row + (size_t)(((slotA >> 3) ^ (d & 7)) * 16 + (slotA & 7) * 2))
        = *(const ushort4*)&hv[0];
    *(ushort4*)(Vg + row + (size_t)(((slotB >> 3) ^ (d & 7)) * 16 + (slotB & 7) * 2))
        = *(const ushort4*)&hv[4];
}

// ---------------------------------------------------------------------------
// attn9 R15: deferred-PV software pipeline (R1 partition).
//
// R4 lesson: occupancy (34%) is NOT the lever - doubling steps/traffic for
// 4 waves/SIMD cost 37%.  The real structure (cycle model, 19cy/MFMA/SIMD):
// per wave-step MFMA ~700cy + VALU ~620cy run SERIALLY (QK->exp->PV chain;
// co-resident waves in lockstep).  Fix INTRA-wave: defer PV one step so
// step c = QK(c) MFMA + exp(c) VALU + PV(c-1) MFMA, all independent ->
// pipes overlap, floor -> max(MFMA,VALU) ~ 700cy.
//
// - 64q x 64d per wave, 32 steps x 32 keys (R1 key split).
// - V double-buffered (PV(c-1) reads VBuf[(c-1)&1], V(c+1) -> other);
//   K single-buffered; pb and flag ping-pong (no copies).
// - ONE vmcnt/step: issue K(c+1) early, {V(c+1),flag(c+1)} at end;
//   top vmcnt(5) retires through K(c) (window-order robust).
//   Prologue vmcnt(4) (flag0 first in queue); final PV vmcnt(0).
// - (256,2): regs ~190-210, 2 waves/SIMD by design; LDS 48KB, 2 blk/CU.
// TRIPWIRE: MfmaUtil/VALUBusy ~40/40 & dur ~84 => scheduler refused the
// interleave -> manual interleave next round.
// ---------------------------------------------------------------------------
#define ISSUE_K(CC)                                                            \
  {                                                                            \
    const uchar* ks_ = kgb + (size_t)(CC) * 16384;                             \
    async16(KB,        ks_ + l16);                                             \
    async16(KB + 1024, ks_ + 1024 + l16);                                      \
    async16(KB + 2048, ks_ + 2048 + l16);                                      \
    async16(KB + 3072, ks_ + 3072 + l16);                                      \
  }
#define ISSUE_V(CC)                                                            \
  {                                                                            \
    uchar* vb_ = VB0 + (size_t)((CC) & 1) * 4096;                              \
    const uchar* vs_ = vgb + (size_t)(CC) * 16384;                             \
    async16(vb_,        vs_ + voff);                                           \
    async16(vb_ + 1024, vs_ + 4096 + voff);                                    \
    async16(vb_ + 2048, vs_ + 8192 + voff);                                    \
    async16(vb_ + 3072, vs_ + 12288 + voff);                                   \
  }

// Step CC: QK(CC)+exp(CC) -> (PBN); PV(CC-1)+dot8(CC-1) from (PBO),(FLG);
// then reload (FLG) = flag(CC+1).  FIRST skips the PV/dot8 phase.
#define ATTN_STEP(CC, TOPC, FLG, PBN, PBO, FIRST)                              \
  {                                                                            \
    asm volatile("s_waitcnt vmcnt(" TOPC ")" ::: "memory");                    \
    f16x8 ka_ = *(const f16x8*)(KB + (size_t)l15 * 128 + ph0);                 \
    f16x8 kb_ = *(const f16x8*)(KB + (size_t)(16 + l15) * 128 + ph0);          \
    f16x8 kc_ = *(const f16x8*)(KB + (size_t)l15 * 128 + ph1);                 \
    f16x8 kd_ = *(const f16x8*)(KB + (size_t)(16 + l15) * 128 + ph1);          \
    asm volatile("s_waitcnt lgkmcnt(0)" ::: "memory");                         \
    if ((CC) + 1 < 32) ISSUE_K((CC) + 1);                                      \
    _Pragma("unroll")                                                          \
    for (int qt = 0; qt < 4; qt++) {                                           \
      f32x4 s0 = mfma16h(ka_, qf[qt][0], zero4);                               \
      s0 = mfma16h(kc_, qf[qt][1], s0);                                        \
      f32x4 s1 = mfma16h(kb_, qf[qt][0], zero4);                               \
      s1 = mfma16h(kd_, qf[qt][1], s1);                                        \
      h16x2 c01 = __builtin_amdgcn_cvt_pkrtz(                                  \
          __builtin_amdgcn_exp2f(s0[0]), __builtin_amdgcn_exp2f(s0[1]));       \
      h16x2 c23 = __builtin_amdgcn_cvt_pkrtz(                                  \
          __builtin_amdgcn_exp2f(s0[2]), __builtin_amdgcn_exp2f(s0[3]));       \
      h16x2 c45 = __builtin_amdgcn_cvt_pkrtz(                                  \
          __builtin_amdgcn_exp2f(s1[0]), __builtin_amdgcn_exp2f(s1[1]));       \
      h16x2 c67 = __builtin_amdgcn_cvt_pkrtz(                                  \
          __builtin_amdgcn_exp2f(s1[2]), __builtin_amdgcn_exp2f(s1[3]));       \
      uint4 pw;                                                                \
      pw.x = __builtin_bit_cast(u32, c01);                                     \
      pw.y = __builtin_bit_cast(u32, c23);                                     \
      pw.z = __builtin_bit_cast(u32, c45);                                     \
      pw.w = __builtin_bit_cast(u32, c67);                                     \
      (PBN)[qt] = __builtin_bit_cast(f16x8, pw);                               \
    }                                                                          \
    if (!(FIRST)) {                                                            \
      const uchar* VBp_ = VB0 + (size_t)(((CC) + 1) & 1) * 4096;               \
      _Pragma("unroll")                                                        \
      for (int dt = 0; dt < 4; dt++) {                                         \
        f16x8 va = *(const f16x8*)(VBp_ + (size_t)(dt * 16 + l15) * 64 + vrd); \
        _Pragma("unroll")                                                      \
        for (int qt = 0; qt < 4; qt++)                                         \
          o[dt][qt] = mfma16h(va, (PBO)[qt], o[dt][qt]);                       \
      }                                                                        \
      _Pragma("unroll")                                                        \
      for (int qt = 0; qt < 4; qt++)                                           \
        lacc[qt] = dot8((PBO)[qt], (FLG), lacc[qt]);                           \
    }                                                                          \
    asm volatile("s_waitcnt lgkmcnt(0)" ::: "memory");                         \
    if ((CC) + 1 < 32) {                                                       \
      ISSUE_V((CC) + 1);                                                       \
      (FLG) = *(const uint4*)(fmw + (size_t)((CC) + 1) * 256);                 \
    }                                                                          \
  }

__global__ __launch_bounds__(256, 2) void attn9(
    const uchar* __restrict__ Qg, const uchar* __restrict__ Kg,
    const uchar* __restrict__ Vg, const uchar* __restrict__ fm16,
    uchar* __restrict__ CTXp)
{
    __shared__ __align__(16) uchar arena[49152];   // 4 waves x [K|V0|V1] 4KB
    float* Os   = (float*)arena;                   // post-loop overlays
    float* Lsh  = (float*)(arena + 18432);         // [4][64]
    float* Lfin = (float*)(arena + 19712);         // [64]

    const int t    = threadIdx.x;
    const int lane = t & 63;
    const int w    = t >> 6;
    const int quad = lane >> 4;
    const int l15  = lane & 15;
    const int x7   = l15 & 7;
    const int hh   = blockIdx.y;
    const int m0   = blockIdx.x * 64;

    const uchar* qgb = Qg + (size_t)hh * (S_LEN * 128);
    const uchar* kgb = Kg + (size_t)hh * (S_LEN * 128) + (size_t)w * 4096;
    const uchar* vgb = Vg + (size_t)hh * 32 * 16384;
    const uchar* fmw = fm16 + w * 64 + quad * 16;

    uchar* WB  = arena + w * 12288;
    uchar* KB  = WB;
    uchar* VB0 = WB + 4096;

    const int l16 = lane * 16;
    const int vphys = ((w * 4 + ((lane & 3) ^ ((lane >> 2) & 3))) ^ ((lane >> 2) & 7));
    const int voff  = (lane >> 2) * 256 + vphys * 16;
    const int vrd   = (quad ^ (l15 & 3)) * 16;
    const int ph0   = (quad ^ x7) * 16;
    const int ph1   = ((4 + quad) ^ x7) * 16;

    // ---- Q fragments -> registers, once ----
    f16x8 qf[4][2];
    #pragma unroll
    for (int qt = 0; qt < 4; qt++)
        #pragma unroll
        for (int ks = 0; ks < 2; ks++)
            qf[qt][ks] = *(const f16x8*)(qgb + (size_t)(m0 + qt * 16 + l15) * 128 +
                                         (size_t)(((ks * 4 + quad) ^ x7) * 16));

    f32x4 o[4][4];
    float lacc[4] = {0.0f, 0.0f, 0.0f, 0.0f};
    const f32x4 zero4 = {0.0f, 0.0f, 0.0f, 0.0f};
    #pragma unroll
    for (int dt = 0; dt < 4; dt++)
        #pragma unroll
        for (int qt = 0; qt < 4; qt++) o[dt][qt] = zero4;

    // ---- prologue: flag(0) FIRST in queue, then K(0), V(0) ----
    uint4 flagA = *(const uint4*)(fmw);
    uint4 flagB = flagA;
    asm volatile("" ::: "memory");
    ISSUE_K(0);
    ISSUE_V(0);

    f16x8 pbE[4], pbO[4];

    // queue math: prologue outstanding {fl0(1),K0(4),V0(4)}=9 -> vmcnt(4)
    // retires fl0+K0.  Steady: top-of-c outstanding {W(c-1)(5),K(c)(4),
    // W(c)(5)}=14 -> vmcnt(5) retires W(c-1)+K(c).  W = {V,flag} window.
    ATTN_STEP(0, "4", flagB, pbE, pbE, true);
    for (int c = 1; c < 31; c += 2) {
        ATTN_STEP(c,     "5", flagA, pbO, pbE, false);
        ATTN_STEP(c + 1, "5", flagB, pbE, pbO, false);
    }
    ATTN_STEP(31, "5", flagA, pbO, pbE, false);

    // ---- peeled final: PV(31) + dot8(31) ----
    asm volatile("s_waitcnt vmcnt(0)" ::: "memory");
    {
        const uchar* VBp_ = VB0 + 4096;            // VBuf[31&1 = 1]
        #pragma unroll
        for (int dt = 0; dt < 4; dt++) {
            f16x8 va = *(const f16x8*)(VBp_ + (size_t)(dt * 16 + l15) * 64 + vrd);
            #pragma unroll
            for (int qt = 0; qt < 4; qt++)
                o[dt][qt] = mfma16h(va, pbO[qt], o[dt][qt]);
        }
        #pragma unroll
        for (int qt = 0; qt < 4; qt++)
            lacc[qt] = dot8(pbO[qt], flagB, lacc[qt]);
    }

    // ---- l finalize: cross-quad reduce in-register, then cross-wave ----
    #pragma unroll
    for (int qt = 0; qt < 4; qt++) {
        float v = lacc[qt];
        v += __shfl_xor(v, 16);
        v += __shfl_xor(v, 32);
        lacc[qt] = v;
    }
    __syncthreads();                 // all waves done; arena reusable
    if (quad == 0) {
        #pragma unroll
        for (int qt = 0; qt < 4; qt++)
            Lsh[w * 64 + qt * 16 + l15] = lacc[qt];
    }
    __syncthreads();
    if (t < 64)
        Lfin[t] = Lsh[t] + Lsh[64 + t] + Lsh[128 + t] + Lsh[192 + t];
    __syncthreads();

    // ---- o merge: plain sum across waves ----
    for (int wv = 0; wv < 4; wv++) {
        if (w == wv) {
            #pragma unroll
            for (int dt = 0; dt < 4; dt++)
                #pragma unroll
                for (int qt = 0; qt < 4; qt++)
                    #pragma unroll
                    for (int r = 0; r < 4; r++) {
                        int q = qt * 16 + l15;
                        int d = dt * 16 + quad * 4 + r;
                        float val = o[dt][qt][r];
                        if (wv == 0) Os[q * 68 + d] = val;
                        else         Os[q * 68 + d] += val;
                    }
        }
        __syncthreads();
    }

    // ---- epilogue: ctx packed fp16, kc = head (feeds Wo GEMM) ----
    #pragma unroll
    for (int i = 0; i < 4; i++) {
        int idx = t + 256 * i;
        int q   = idx >> 4;
        int c4  = (idx & 15) * 4;
        float inv = 1.0f / Lfin[q];
        float4 v = *(const float4*)&Os[q * 68 + c4];
        int m = m0 + q;
        __align__(8) _Float16 h[4];
        h[0] = (_Float16)(v.x * inv);
        h[1] = (_Float16)(v.y * inv);
        h[2] = (_Float16)(v.z * inv);
        h[3] = (_Float16)(v.w * inv);
        size_t base = ((size_t)(m * 16 + hh)) * 128 +
                      (size_t)((((c4 >> 3) ^ (m & 7))) * 16) + (c4 & 7) * 2;
        *(ushort4*)(CTXp + base) = *(const ushort4*)h;
    }
}

// ---------------------------------------------------------------------------
extern "C" void kernel_launch(void* const* d_in, const int* in_sizes, int n_in,
                              void* d_out, int out_size, void* d_ws, size_t ws_size,
                              hipStream_t stream)
{
    const float* x   = (const float*)d_in[0];
    const float* Wq  = (const float*)d_in[1];
    const float* Wk  = (const float*)d_in[2];
    const float* Wv  = (const float*)d_in[3];
    const float* Wo  = (const float*)d_in[4];
    const int* amask = (const int*)d_in[5];
    float* out = (float*)d_out;
    float* ws  = (float*)d_ws;

    // byte-offset workspace map:
    //   QKVf  fp32 [48][4096][64]   bytes [0, 50331648)
    //   Xp    fp16 packed x (8.4MB) bytes [50331648, 58720256)  later = Qg
    //   Wt4   fp16 packed W^T x4    bytes [58720256, 67108864)  (2MB each)
    //   Vg    fp16 V tiles (8.4MB)  bytes [67108864, 75497472)
    //   Fm16  fp16 flags (8KB)      bytes [75497472, 75505664)
    //   Kg    = bytes [33554432, 41943040)   (over Vf, dead after v_pack)
    //   CTXp  = bytes [0, 8388608)           (over Qf, dead after rope)
    float* QKVf = ws;
    uchar* Xp   = (uchar*)ws + 50331648;
    uchar* Wt4  = (uchar*)ws + 58720256;
    uchar* Vg   = (uchar*)ws + 67108864;
    _Float16* Fm16 = (_Float16*)((uchar*)ws + 75497472);
    uchar* Qg   = Xp;
    uchar* Kg   = (uchar*)ws + 33554432;
    uchar* CTXp = (uchar*)ws;

    dim3 blk(256);

    pack_x<<<2048, blk, 0, stream>>>(x, Xp, amask, Fm16);
    pack_w4<<<2048, blk, 0, stream>>>(Wq, Wk, Wv, Wo, Wt4);

    // fused QKV projection: N = 3072, head-major out (heads 0..47)
    gemm_f16<<<dim3(24, 32), blk, 0, stream>>>(Xp, Wt4, QKVf, 1);

    // V pack BEFORE rope (Kg aliases Vf region); masked rows zeroed, slots permuted
    v_pack<<<2048, blk, 0, stream>>>(QKVf + 8388608, amask, Vg);
    rope_pack<<<4096, blk, 0, stream>>>(QKVf, Qg, Kg);

    attn9<<<dim3(S_LEN / 64, NHEADS), blk, 0, stream>>>(Qg, Kg, Vg,
                                                        (const uchar*)Fm16, CTXp);

    // output projection: N = 1024, row-major out (Wo at Wt4 + 3*2MB)
    gemm_f16<<<dim3(8, 32), blk, 0, stream>>>(CTXp, Wt4 + 6291456, out, 0);
}

// Round 6
// 215.510 us; speedup vs baseline: 1.2141x; 1.1526x over previous
//
#include <hip/hip_runtime.h>
#include <cstdint>
#include <cstddef>

// Problem constants (B=1, S=4096, H=1024, 16 heads x 64)
#define S_LEN 4096
#define NHEADS 16
#define HD 64
#define HDIM 1024

typedef _Float16 f16x8 __attribute__((ext_vector_type(8)));
typedef __fp16 h16x2 __attribute__((ext_vector_type(2)));   // cvt_pkrtz native
typedef float f32x4 __attribute__((ext_vector_type(4)));
typedef unsigned char uchar;
typedef unsigned int u32;

__device__ __forceinline__ f32x4 mfma16h(f16x8 a, f16x8 b, f32x4 c) {
    return __builtin_amdgcn_mfma_f32_16x16x32_f16(a, b, c, 0, 0, 0);
}
// async global->LDS, 16B/lane; lds must be wave-uniform base (HW adds lane*16)
__device__ __forceinline__ void async16(void* lds, const void* g) {
    __builtin_amdgcn_global_load_lds(
        (const __attribute__((address_space(1))) u32*)g,
        (__attribute__((address_space(3))) u32*)lds, 16, 0, 0);
}

// ---------------------------------------------------------------------------
// Packed fp16 format: per 64-elem logical row, a 128B record of 8 x 16B
// blocks XOR-swizzled: element e of row r lives at ((e>>3)^(r&7))*16+(e&7)*2.
//
// KEY PERMUTATION (attn): within each wave's 32-key slice, key kt*16+q*4+r
// is stored at slot q*8+kt*4+r.  With V rows and l-flags permuted by this
// sigma, the MFMA C-layout P values (key=quad*4+r per kt) ARE the PV
// B-operand fragment (k-slot quad*8+j) in-register -> P never touches LDS.
//
// R16: rope_pack + v_pack FUSED into the QKV GEMM epilogue (RoPE/pack/sigma
// from fp32 accumulators; partner via shfl_xor(acc,1)).  pack_x + pack_w4
// merged.  attn9 reverted to the R1 version (best measured 83.8us; R4/R5
// occupancy & pipeline attacks both regressed).  7 kernels -> 4.
// ---------------------------------------------------------------------------

// blocks [0,2048): x [4096][1024] fp32 -> Xp packed rows + sigma fp16 flags
// blocks [2048,4096): 4 weight matrices -> fp16 B^T packed rows
__global__ __launch_bounds__(256) void pack_xw(
    const float* __restrict__ X, uchar* __restrict__ P,
    const int* __restrict__ M, _Float16* __restrict__ FM16,
    const float* __restrict__ W0, const float* __restrict__ W1,
    const float* __restrict__ W2, const float* __restrict__ W3,
    uchar* __restrict__ PW)
{
    if (blockIdx.x < 2048) {
        int id = blockIdx.x * 256 + threadIdx.x;       // 4096*128
        int m = id >> 7, g = id & 127;
        int kc = g >> 3, b = g & 7;
        float v[8];
        *(float4*)&v[0] = *(const float4*)&X[(size_t)m * HDIM + kc * 64 + b * 8];
        *(float4*)&v[4] = *(const float4*)&X[(size_t)m * HDIM + kc * 64 + b * 8 + 4];
        __align__(16) _Float16 h[8];
        #pragma unroll
        for (int i = 0; i < 8; i++) h[i] = (_Float16)v[i];
        size_t base = ((size_t)(m * 16 + kc)) * 128 + (size_t)((b ^ (m & 7)) * 16);
        *(uint4*)(P + base) = *(const uint4*)h;
        if (id < S_LEN) {
            int c = id >> 7, k128 = id & 127;
            int w = k128 >> 5, k32 = k128 & 31;
            int q = (k32 >> 2) & 3, kt = k32 >> 4, r = k32 & 3;
            FM16[c * 128 + w * 32 + q * 8 + kt * 4 + r] =
                (_Float16)((M[id] == 0) ? 0.0f : 1.0f);
        }
    } else {
        int id = (blockIdx.x - 2048) * 256 + threadIdx.x;   // 4*128*1024
        int wsel = id >> 17;
        int lid  = id & 131071;
        int g = lid >> 10, n = lid & 1023;
        int kc = g >> 3, b = g & 7;
        const float* W = (wsel == 0) ? W0 : (wsel == 1) ? W1 : (wsel == 2) ? W2 : W3;
        uchar* dst = PW + (size_t)wsel * 2097152;
        float v[8];
        #pragma unroll
        for (int j = 0; j < 8; j++)
            v[j] = W[(size_t)(kc * 64 + b * 8 + j) * HDIM + n];
        __align__(16) _Float16 h[8];
        #pragma unroll
        for (int i = 0; i < 8; i++) h[i] = (_Float16)v[i];
        size_t base = ((size_t)(n * 16 + kc)) * 128 + (size_t)((b ^ (n & 7)) * 16);
        *(uint4*)(dst + base) = *(const uint4*)h;
    }
}

// ---------------------------------------------------------------------------
// QKV GEMM with fused RoPE/pack epilogue.  N = 3072 (heads 0-15 Q, 16-31 K,
// 32-47 V).  Main loop identical to gemm_f16; epilogue branches per wave:
//  Q/K: RoPE from fp32 acc (partner d^1 via shfl_xor(acc,1); theta = m *
//       10000^(-(d&31)/32); even d: own*cos - par*sin; odd: own*cos + par*sin;
//       Q scaled 0.125*log2e) -> packed fp16 row records.
//  V:   mask-zero + sigma slot-permute -> 16KB head tiles (ushort4 granules,
//       slot = wv*32 + quad*8 + (mt&1)*4 + r, row kc2 = blockIdx.y).
// ---------------------------------------------------------------------------
__global__ __launch_bounds__(256) void gemm_qkv(
    const uchar* __restrict__ Ap, const uchar* __restrict__ Bp,
    const int* __restrict__ M,
    uchar* __restrict__ Qg, uchar* __restrict__ Kg, uchar* __restrict__ Vg)
{
    __shared__ __align__(16) uchar AB[65536];
    const int t = threadIdx.x, lane = t & 63, w = t >> 6;
    const int quad = lane >> 4, l15 = lane & 15, x7 = l15 & 7;
    const int m0 = blockIdx.y * 128, n0 = blockIdx.x * 128;
    const int wm = (w >> 1) * 64, wn = (w & 1) * 64;

    f32x4 acc[4][4];
    const f32x4 zero4 = {0.0f, 0.0f, 0.0f, 0.0f};
    #pragma unroll
    for (int mt = 0; mt < 4; mt++)
        #pragma unroll
        for (int nt = 0; nt < 4; nt++) acc[mt][nt] = zero4;

    #pragma unroll
    for (int i = 0; i < 4; i++) {
        int idx = i * 256 + t;
        int row = idx >> 3, blk = idx & 7;
        int ldso = (idx & ~63) * 16;
        async16(AB + ldso,         Ap + ((size_t)((m0 + row) * 16 + 0)) * 128 + blk * 16);
        async16(AB + 16384 + ldso, Bp + ((size_t)((n0 + row) * 16 + 0)) * 128 + blk * 16);
    }

    for (int kc = 0; kc < 16; kc++) {
        uchar* As = AB + (kc & 1) * 32768;
        uchar* Bs = As + 16384;
        __syncthreads();
        if (kc + 1 < 16) {
            uchar* An = AB + ((kc + 1) & 1) * 32768;
            #pragma unroll
            for (int i = 0; i < 4; i++) {
                int idx = i * 256 + t;
                int row = idx >> 3, blk = idx & 7;
                int ldso = (idx & ~63) * 16;
                async16(An + ldso,
                        Ap + ((size_t)((m0 + row) * 16 + kc + 1)) * 128 + blk * 16);
                async16(An + 16384 + ldso,
                        Bp + ((size_t)((n0 + row) * 16 + kc + 1)) * 128 + blk * 16);
            }
        }
        #pragma unroll
        for (int ks = 0; ks < 2; ks++) {
            const int phys = ((ks * 4 + quad) ^ x7) * 16;
            f16x8 ah[4];
            #pragma unroll
            for (int mt = 0; mt < 4; mt++)
                ah[mt] = *(const f16x8*)(As + (size_t)(wm + mt * 16 + l15) * 128 + phys);
            #pragma unroll
            for (int nt = 0; nt < 4; nt++) {
                f16x8 bh = *(const f16x8*)(Bs + (size_t)(wn + nt * 16 + l15) * 128 + phys);
                #pragma unroll
                for (int mt = 0; mt < 4; mt++)
                    acc[mt][nt] = mfma16h(ah[mt], bh, acc[mt][nt]);
            }
        }
    }

    const int headN = (n0 + wn) >> 6;      // 0..47, uniform per wave
    if (headN < 32) {
        // ---- Q/K: RoPE + packed fp16 row records ----
        const bool isQ = headN < 16;
        uchar* dst = isQ ? Qg : Kg;
        const int hh = headN & 15;
        const float scale = isQ ? 0.18033688011112042f : 1.0f;  // 0.125*log2e
        const float L32 = 13.287712379549449f / 32.0f;          // log2(1e4)/32
        #pragma unroll
        for (int nt = 0; nt < 4; nt++) {
            const int d = nt * 16 + l15;
            const float f = __builtin_amdgcn_exp2f(-(float)(d & 31) * L32);
            const float sgn = (d & 1) ? 1.0f : -1.0f;
            #pragma unroll
            for (int mt = 0; mt < 4; mt++)
                #pragma unroll
                for (int r = 0; r < 4; r++) {
                    int m = m0 + wm + mt * 16 + quad * 4 + r;
                    float own = acc[mt][nt][r];
                    float par = __shfl_xor(own, 1);   // partner d^1, same m
                    float th = (float)m * f;
                    float val = (own * __cosf(th) + sgn * par * __sinf(th)) * scale;
                    _Float16 hv = (_Float16)val;
                    size_t base = ((size_t)(hh * S_LEN + m)) * 128 +
                                  (size_t)(((d >> 3) ^ (m & 7)) * 16) + (d & 7) * 2;
                    *(_Float16*)(dst + base) = hv;
                }
        }
    } else {
        // ---- V: mask-zero + sigma slot-permute into 16KB head tiles ----
        const int head = headN - 32;
        const int kc2 = m0 >> 7;           // = blockIdx.y
        #pragma unroll
        for (int mt = 0; mt < 4; mt++) {
            int mb = m0 + wm + mt * 16 + quad * 4;   // key base (r=0)
            int4 mk = *(const int4*)&M[mb];
            int wv = (wm + mt * 16) >> 5;
            int kt = mt & 1;
            int slotbase = wv * 32 + quad * 8 + kt * 4;
            size_t off = (size_t)(((slotbase >> 3) ^ 0) * 16);  // d-XOR added below
            #pragma unroll
            for (int nt = 0; nt < 4; nt++) {
                const int d = nt * 16 + l15;
                __align__(8) _Float16 hv[4];
                hv[0] = (mk.x == 0) ? (_Float16)0.0f : (_Float16)acc[mt][nt][0];
                hv[1] = (mk.y == 0) ? (_Float16)0.0f : (_Float16)acc[mt][nt][1];
                hv[2] = (mk.z == 0) ? (_Float16)0.0f : (_Float16)acc[mt][nt][2];
                hv[3] = (mk.w == 0) ? (_Float16)0.0f : (_Float16)acc[mt][nt][3];
                size_t row = ((size_t)(head * 32 + kc2)) * 16384 + (size_t)d * 256;
                size_t boff = (size_t)((((slotbase >> 3) ^ (d & 7)) * 16) +
                                       (slotbase & 7) * 2);
                *(ushort4*)(Vg + row + boff) = *(const ushort4*)hv;
            }
            (void)off;
        }
    }
}

// ---------------------------------------------------------------------------
// Wo GEMM: fp16 MFMA, row-major fp32 out (unchanged main loop).
// ---------------------------------------------------------------------------
__global__ __launch_bounds__(256) void gemm_f16(
    const uchar* __restrict__ Ap, const uchar* __restrict__ Bp,
    float* __restrict__ C)
{
    __shared__ __align__(16) uchar AB[65536];
    const int t = threadIdx.x, lane = t & 63, w = t >> 6;
    const int quad = lane >> 4, l15 = lane & 15, x7 = l15 & 7;
    const int m0 = blockIdx.y * 128, n0 = blockIdx.x * 128;
    const int wm = (w >> 1) * 64, wn = (w & 1) * 64;

    f32x4 acc[4][4];
    const f32x4 zero4 = {0.0f, 0.0f, 0.0f, 0.0f};
    #pragma unroll
    for (int mt = 0; mt < 4; mt++)
        #pragma unroll
        for (int nt = 0; nt < 4; nt++) acc[mt][nt] = zero4;

    #pragma unroll
    for (int i = 0; i < 4; i++) {
        int idx = i * 256 + t;
        int row = idx >> 3, blk = idx & 7;
        int ldso = (idx & ~63) * 16;
        async16(AB + ldso,         Ap + ((size_t)((m0 + row) * 16 + 0)) * 128 + blk * 16);
        async16(AB + 16384 + ldso, Bp + ((size_t)((n0 + row) * 16 + 0)) * 128 + blk * 16);
    }

    for (int kc = 0; kc < 16; kc++) {
        uchar* As = AB + (kc & 1) * 32768;
        uchar* Bs = As + 16384;
        __syncthreads();
        if (kc + 1 < 16) {
            uchar* An = AB + ((kc + 1) & 1) * 32768;
            #pragma unroll
            for (int i = 0; i < 4; i++) {
                int idx = i * 256 + t;
                int row = idx >> 3, blk = idx & 7;
                int ldso = (idx & ~63) * 16;
                async16(An + ldso,
                        Ap + ((size_t)((m0 + row) * 16 + kc + 1)) * 128 + blk * 16);
                async16(An + 16384 + ldso,
                        Bp + ((size_t)((n0 + row) * 16 + kc + 1)) * 128 + blk * 16);
            }
        }
        #pragma unroll
        for (int ks = 0; ks < 2; ks++) {
            const int phys = ((ks * 4 + quad) ^ x7) * 16;
            f16x8 ah[4];
            #pragma unroll
            for (int mt = 0; mt < 4; mt++)
                ah[mt] = *(const f16x8*)(As + (size_t)(wm + mt * 16 + l15) * 128 + phys);
            #pragma unroll
            for (int nt = 0; nt < 4; nt++) {
                f16x8 bh = *(const f16x8*)(Bs + (size_t)(wn + nt * 16 + l15) * 128 + phys);
                #pragma unroll
                for (int mt = 0; mt < 4; mt++)
                    acc[mt][nt] = mfma16h(ah[mt], bh, acc[mt][nt]);
            }
        }
    }

    #pragma unroll
    for (int mt = 0; mt < 4; mt++)
        #pragma unroll
        for (int nt = 0; nt < 4; nt++)
            #pragma unroll
            for (int r = 0; r < 4; r++) {
                int m = m0 + wm + mt * 16 + quad * 4 + r;
                int n = n0 + wn + nt * 16 + l15;
                C[(size_t)m * HDIM + n] = acc[mt][nt][r];
            }
}

// ---------------------------------------------------------------------------
// attn9: R1 version verbatim (best measured 83.8us).  Barrier-free wave
// pipeline, P in registers, single-buffered K, vmcnt steady (5,4),
// peel step0 (4,4) / step31 (4,0), launch_bounds(256,2).
// ---------------------------------------------------------------------------
#define ISSUE_K(CC)                                                            \
  {                                                                            \
    const uchar* ks_ = kgb + (size_t)(CC) * 16384;                             \
    async16(KB,        ks_ + l16);                                             \
    async16(KB + 1024, ks_ + 1024 + l16);                                      \
    async16(KB + 2048, ks_ + 2048 + l16);                                      \
    async16(KB + 3072, ks_ + 3072 + l16);                                      \
  }
#define ISSUE_V(CC)                                                            \
  {                                                                            \
    const uchar* vs_ = vgb + (size_t)(CC) * 16384;                             \
    async16(VB,        vs_ + voff);                                            \
    async16(VB + 1024, vs_ + 4096 + voff);                                     \
    async16(VB + 2048, vs_ + 8192 + voff);                                     \
    async16(VB + 3072, vs_ + 12288 + voff);                                    \
  }

#define ATTN_STEP(CC, TOPC, MIDC, FLG)                                         \
  {                                                                            \
    asm volatile("s_waitcnt vmcnt(" TOPC ")" ::: "memory");                    \
    const int ph0_ = (quad ^ x7) * 16;                                         \
    const int ph1_ = ((4 + quad) ^ x7) * 16;                                   \
    f16x8 ka_ = *(const f16x8*)(KB + (size_t)l15 * 128 + ph0_);                \
    f16x8 kb_ = *(const f16x8*)(KB + (size_t)(16 + l15) * 128 + ph0_);         \
    f16x8 kc_ = *(const f16x8*)(KB + (size_t)l15 * 128 + ph1_);                \
    f16x8 kd_ = *(const f16x8*)(KB + (size_t)(16 + l15) * 128 + ph1_);         \
    asm volatile("s_waitcnt lgkmcnt(0)" ::: "memory");                         \
    if ((CC) + 1 < 32) ISSUE_K((CC) + 1);                                      \
    f16x8 pb[4];                                                               \
    _Pragma("unroll")                                                          \
    for (int qt = 0; qt < 4; qt++) {                                           \
      f32x4 s0 = mfma16h(ka_, qf[qt][0], zero4);                               \
      s0 = mfma16h(kc_, qf[qt][1], s0);                                        \
      f32x4 s1 = mfma16h(kb_, qf[qt][0], zero4);                               \
      s1 = mfma16h(kd_, qf[qt][1], s1);                                        \
      h16x2 c01 = __builtin_amdgcn_cvt_pkrtz(                                  \
          __builtin_amdgcn_exp2f(s0[0]), __builtin_amdgcn_exp2f(s0[1]));       \
      h16x2 c23 = __builtin_amdgcn_cvt_pkrtz(                                  \
          __builtin_amdgcn_exp2f(s0[2]), __builtin_amdgcn_exp2f(s0[3]));       \
      h16x2 c45 = __builtin_amdgcn_cvt_pkrtz(                                  \
          __builtin_amdgcn_exp2f(s1[0]), __builtin_amdgcn_exp2f(s1[1]));       \
      h16x2 c67 = __builtin_amdgcn_cvt_pkrtz(                                  \
          __builtin_amdgcn_exp2f(s1[2]), __builtin_amdgcn_exp2f(s1[3]));       \
      uint4 pw;                                                                \
      pw.x = __builtin_bit_cast(u32, c01);                                     \
      pw.y = __builtin_bit_cast(u32, c23);                                     \
      pw.z = __builtin_bit_cast(u32, c45);                                     \
      pw.w = __builtin_bit_cast(u32, c67);                                     \
      pb[qt] = __builtin_bit_cast(f16x8, pw);                                  \
    }                                                                          \
    asm volatile("s_waitcnt vmcnt(" MIDC ")" ::: "memory");                    \
    _Pragma("unroll")                                                          \
    for (int dt = 0; dt < 4; dt++) {                                           \
      f16x8 va = *(const f16x8*)(VB + (size_t)(dt * 16 + l15) * 64 + vrd);     \
      _Pragma("unroll")                                                        \
      for (int qt = 0; qt < 4; qt++)                                           \
        o[dt][qt] = mfma16h(va, pb[qt], o[dt][qt]);                            \
    }                                                                          \
    _Pragma("unroll")                                                          \
    for (int qt = 0; qt < 4; qt++)                                             \
      lacc[qt] = mfma16h((FLG), pb[qt], lacc[qt]);                             \
    asm volatile("s_waitcnt lgkmcnt(0)" ::: "memory");                         \
    if ((CC) + 1 < 32) ISSUE_V((CC) + 1);                                      \
    if ((CC) + 2 < 32) (FLG) = *(const f16x8*)(fmw + (size_t)((CC) + 2) * 256);\
  }

__global__ __launch_bounds__(256, 2) void attn9(
    const uchar* __restrict__ Qg, const uchar* __restrict__ Kg,
    const uchar* __restrict__ Vg, const uchar* __restrict__ fm16,
    uchar* __restrict__ CTXp)
{
    __shared__ __align__(16) uchar arena[32768];   // 4 waves x [K|V] 4KB each
    __shared__ float Lsh[4][64];
    __shared__ float Lfin[64];
    float* Os = (float*)arena;                     // merge overlay (after loop)

    const int t    = threadIdx.x;
    const int lane = t & 63;
    const int w    = t >> 6;
    const int quad = lane >> 4;
    const int l15  = lane & 15;
    const int x7   = l15 & 7;
    const int hh   = blockIdx.y;
    const int m0   = blockIdx.x * 64;

    const uchar* qgb = Qg + (size_t)hh * (S_LEN * 128);
    const uchar* kgb = Kg + (size_t)hh * (S_LEN * 128) + (size_t)w * 4096;
    const uchar* vgb = Vg + (size_t)hh * 32 * 16384;
    const uchar* fmw = fm16 + w * 64 + quad * 16;

    uchar* WB = arena + w * 8192;
    uchar* KB = WB;
    uchar* VB = WB + 4096;

    const int l16 = lane * 16;
    const int vphys = ((w * 4 + ((lane & 3) ^ ((lane >> 2) & 3))) ^ ((lane >> 2) & 7));
    const int voff  = (lane >> 2) * 256 + vphys * 16;
    const int vrd   = (quad ^ (l15 & 3)) * 16;

    // ---- Q fragments -> registers, once ----
    f16x8 qf[4][2];
    #pragma unroll
    for (int qt = 0; qt < 4; qt++)
        #pragma unroll
        for (int ks = 0; ks < 2; ks++)
            qf[qt][ks] = *(const f16x8*)(qgb + (size_t)(m0 + qt * 16 + l15) * 128 +
                                         (size_t)(((ks * 4 + quad) ^ x7) * 16));

    f32x4 o[4][4], lacc[4];
    const f32x4 zero4 = {0.0f, 0.0f, 0.0f, 0.0f};
    #pragma unroll
    for (int dt = 0; dt < 4; dt++)
        #pragma unroll
        for (int qt = 0; qt < 4; qt++) o[dt][qt] = zero4;
    #pragma unroll
    for (int qt = 0; qt < 4; qt++) lacc[qt] = zero4;

    // ---- prologue: flags first, then DMA issues (order pinned by asm) ----
    f16x8 flagA = *(const f16x8*)(fmw);
    f16x8 flagB = *(const f16x8*)(fmw + 256);
    asm volatile("" ::: "memory");
    ISSUE_K(0);
    ISSUE_V(0);

    ATTN_STEP(0, "4", "4", flagA);
    ATTN_STEP(1, "5", "4", flagB);
    for (int c = 2; c < 30; c += 2) {
        ATTN_STEP(c,     "5", "4", flagA);
        ATTN_STEP(c + 1, "5", "4", flagB);
    }
    ATTN_STEP(30, "5", "4", flagA);
    ATTN_STEP(31, "4", "0", flagB);

    // ---- l finalize: lane holds full slice sum (key-dim summed by MFMA) ----
    __syncthreads();                 // all waves done; arena reusable
    if (quad == 0) {
        #pragma unroll
        for (int qt = 0; qt < 4; qt++)
            Lsh[w][qt * 16 + l15] = lacc[qt][0];
    }
    __syncthreads();
    if (t < 64)
        Lfin[t] = Lsh[0][t] + Lsh[1][t] + Lsh[2][t] + Lsh[3][t];
    __syncthreads();

    // ---- o merge: plain sum across waves ----
    for (int wv = 0; wv < 4; wv++) {
        if (w == wv) {
            #pragma unroll
            for (int dt = 0; dt < 4; dt++)
                #pragma unroll
                for (int qt = 0; qt < 4; qt++)
                    #pragma unroll
                    for (int r = 0; r < 4; r++) {
                        int q = qt * 16 + l15;
                        int d = dt * 16 + quad * 4 + r;
                        float val = o[dt][qt][r];
                        if (wv == 0) Os[q * 68 + d] = val;
                        else         Os[q * 68 + d] += val;
                    }
        }
        __syncthreads();
    }

    // ---- epilogue: ctx packed fp16, kc = head (feeds Wo GEMM) ----
    #pragma unroll
    for (int i = 0; i < 4; i++) {
        int idx = t + 256 * i;
        int q   = idx >> 4;
        int c4  = (idx & 15) * 4;
        float inv = 1.0f / Lfin[q];
        float4 v = *(const float4*)&Os[q * 68 + c4];
        int m = m0 + q;
        __align__(8) _Float16 h[4];
        h[0] = (_Float16)(v.x * inv);
        h[1] = (_Float16)(v.y * inv);
        h[2] = (_Float16)(v.z * inv);
        h[3] = (_Float16)(v.w * inv);
        size_t base = ((size_t)(m * 16 + hh)) * 128 +
                      (size_t)((((c4 >> 3) ^ (m & 7))) * 16) + (c4 & 7) * 2;
        *(ushort4*)(CTXp + base) = *(const ushort4*)h;
    }
}

// ---------------------------------------------------------------------------
extern "C" void kernel_launch(void* const* d_in, const int* in_sizes, int n_in,
                              void* d_out, int out_size, void* d_ws, size_t ws_size,
                              hipStream_t stream)
{
    const float* x   = (const float*)d_in[0];
    const float* Wq  = (const float*)d_in[1];
    const float* Wk  = (const float*)d_in[2];
    const float* Wv  = (const float*)d_in[3];
    const float* Wo  = (const float*)d_in[4];
    const int* amask = (const int*)d_in[5];
    float* out = (float*)d_out;

    // byte-offset workspace map (no fp32 QKV intermediate anymore):
    //   Xp    fp16 packed x (8.4MB)  [0, 8388608)        later = CTXp
    //   Wt4   fp16 packed W^T x4     [8388608, 16777216)
    //   Qg    fp16 rope'd Q (8.4MB)  [16777216, 25165824)
    //   Kg    fp16 rope'd K (8.4MB)  [25165824, 33554432)
    //   Vg    fp16 V tiles (8.4MB)   [33554432, 41943040)
    //   Fm16  fp16 flags (8KB)       [41943040, 41951232)
    uchar* Xp   = (uchar*)d_ws;
    uchar* Wt4  = (uchar*)d_ws + 8388608;
    uchar* Qg   = (uchar*)d_ws + 16777216;
    uchar* Kg   = (uchar*)d_ws + 25165824;
    uchar* Vg   = (uchar*)d_ws + 33554432;
    _Float16* Fm16 = (_Float16*)((uchar*)d_ws + 41943040);
    uchar* CTXp = Xp;                      // Xp dead after gemm_qkv

    dim3 blk(256);

    pack_xw<<<4096, blk, 0, stream>>>(x, Xp, amask, Fm16, Wq, Wk, Wv, Wo, Wt4);

    // fused QKV projection + RoPE/pack/sigma epilogue: N = 3072
    gemm_qkv<<<dim3(24, 32), blk, 0, stream>>>(Xp, Wt4, amask, Qg, Kg, Vg);

    attn9<<<dim3(S_LEN / 64, NHEADS), blk, 0, stream>>>(Qg, Kg, Vg,
                                                        (const uchar*)Fm16, CTXp);

    // output projection: N = 1024, row-major out (Wo at Wt4 + 3*2MB)
    gemm_f16<<<dim3(8, 32), blk, 0, stream>>>(CTXp, Wt4 + 6291456, out);
}